// Round 10
// baseline (437.418 us; speedup 1.0000x reference)
//
#include <hip/hip_runtime.h>
#include <stdint.h>

// Fused attention: S=(x1@x2^T)*0.2; P=softmax(S); P=mask?P/0.9:0; O=P@x3
// B=16, SQ=SK=2048, D=DV=128. fp32 in/out, int32 mask, bf16 MFMA compute.
//
// R13 = R7 (best main: 124us) with ALL s_setprio REMOVED. One variable.
// Rationale: R12 falsified the LDS-pipe theory (removing 8 ds_read + half
// staging made main WORSE, 138 vs 124 — per-tile K loads exposed L2 latency).
// All of {HBM BW, occupancy, barrier drain, LDS pipe, mask stream} are now
// falsified; every pipe <20% busy vs the 9100cyc/tile wall. Remaining
// candidate: scheduler starvation from setprio(1) around MFMA — m190 measured
// setprio as a REGRESSION on barrier-synced multi-wave kernels (our regime;
// m191's +7TF was independent 1-wave blocks). With 2 co-resident blocks, A's
// prio-1 MFMA waves starve B's prio-0 staging waves -> blocks serialize
// instead of interleaving phases.
//  Carried from R7: 64q x 64k block, 4 waves (32q x 32k each), grid 512 =
//  2 blocks/CU; K/V LDS double-buffer via XOR-swizzled Kz/Vz global layouts +
//  linear global_load_lds dest (rule #21), ONE __syncthreads per tile;
//  in-loop coalesced mask dword loads ping-ponged one tile ahead; exp2
//  static-max softmax p=exp2(s*0.28853901-17.3123405); XCD-chunked swizzle;
//  v_cvt_pk_bf16_f32 packing; cross-wk epilogue combine via oxch.
//  Fallback (ws < 16MB): R4 kernel.

#define B_   16
#define SQ_  2048
#define SK_  2048
#define D_   128
#define DV_  128
#define BK   64
#define NT   (SK_ / BK)   // 32 tiles

typedef short  s16x8 __attribute__((ext_vector_type(8)));   // MFMA A/B frag
typedef float  f32x4 __attribute__((ext_vector_type(4)));   // MFMA C/D frag
typedef unsigned int u32x4 __attribute__((ext_vector_type(4)));
typedef unsigned short u16;
typedef unsigned int   u32;

// f32 pair -> packed bf16x2, RNE, single instruction (no builtin on gfx950).
__device__ __forceinline__ u32 pk2(float a, float b) {
    u32 r;
    asm("v_cvt_pk_bf16_f32 %0, %1, %2" : "=v"(r) : "v"(a), "v"(b));
    return r;
}
__device__ __forceinline__ u16 f2bf(float f) { return (u16)pk2(f, 0.0f); }

// async global->LDS, 16B per lane. dst = wave-uniform base (HW adds lane*16).
__device__ __forceinline__ void gload16(void* lds, const void* g) {
    __builtin_amdgcn_global_load_lds((const __attribute__((address_space(1))) u32*)g,
                                     (__attribute__((address_space(3))) u32*)lds,
                                     16, 0, 0);
}

// ---------------- pre-pass: K -> bf16, bank-swizzled ----------------
// Kz[b][k][c] with c = col ^ ((k&7)<<3). 8 MB.
__global__ __launch_bounds__(256)
void prep_k(const float* __restrict__ Kg, u16* __restrict__ Kz)
{
    int g   = blockIdx.x * 256 + threadIdx.x;   // 524288 = 16*2048*16
    int b   = g >> 15;
    int rem = g & 32767;
    int k   = rem >> 4;
    int grp = rem & 15;
    const float* src = Kg + ((size_t)b * SK_ + k) * D_ + grp * 8;
    float4 x = *(const float4*)(src);
    float4 y = *(const float4*)(src + 4);
    u32x4 w = { pk2(x.x, x.y), pk2(x.z, x.w), pk2(y.x, y.y), pk2(y.z, y.w) };
    int c = (grp * 8) ^ ((k & 7) << 3);
    *(u32x4*)(&Kz[((size_t)b * SK_ + k) * D_ + c]) = w;
}

// ---------------- pre-pass: V -> transposed bf16 tiles, swizzled ----------------
// Vz[b][kt][dv][c] with c = k_local ^ ((dv&7)<<3); tile = 128x64 bf16 = 16KB.
__global__ __launch_bounds__(256)
void prep_v(const float* __restrict__ Vg, u16* __restrict__ Vz)
{
    int g  = blockIdx.x * 256 + threadIdx.x;    // 524288 = 16*32*8*128
    int dv = g & 127;
    int kg = (g >> 7) & 7;
    int kt = (g >> 10) & 31;
    int b  = g >> 15;
    const float* src = Vg + ((size_t)b * SK_ + kt * 64 + kg * 8) * DV_ + dv;
    float v[8];
    #pragma unroll
    for (int jj = 0; jj < 8; ++jj) v[jj] = src[(size_t)jj * DV_];
    u32x4 w = { pk2(v[0], v[1]), pk2(v[2], v[3]), pk2(v[4], v[5]), pk2(v[6], v[7]) };
    int c = (kg * 8) ^ ((dv & 7) << 3);
    *(u32x4*)(&Vz[(((size_t)b * 32 + kt) * 128 + dv) * 64 + c]) = w;
}

// ---------------- main kernel ----------------
// One tile step. CUR/NXT: LDS buffer indices; MC/MN: mask reg ping-pong.
// exp(0.2*s - 12) == exp2(s*0.28853901 - 17.3123405). NO setprio (R13).
#define STEP(IT, CUR, NXT, MC, MN)                                            \
  {                                                                           \
    if ((IT) + 1 < NT) {   /* issue next tile's staging + mask loads now */   \
      const u16* Kt = Kz + kvbase + (size_t)((IT) + 1) * 8192;                \
      const u16* Vt = Vz + kvbase + (size_t)((IT) + 1) * 8192;                \
      _Pragma("unroll")                                                       \
      for (int i = 0; i < 4; ++i) {                                           \
        int c16 = (wave * 4 + i) * 512;                                       \
        gload16(&Kbuf[NXT][c16], &Kt[c16 + lane * 8]);                        \
        gload16(&Vbuf[NXT][c16], &Vt[c16 + lane * 8]);                        \
      }                                                                       \
      _Pragma("unroll")                                                       \
      for (int qs = 0; qs < 2; ++qs)                                          \
        _Pragma("unroll")                                                     \
        for (int t = 0; t < 2; ++t)                                           \
          _Pragma("unroll")                                                   \
          for (int r = 0; r < 4; ++r)                                         \
            MN[qs][t][r] = mbase[(size_t)(qs * 16 + r) * SK_                  \
                                 + ((IT) + 1) * 64 + t * 16];                 \
    }                                                                         \
    f32x4 s[2][2];                                                            \
    _Pragma("unroll")                                                         \
    for (int qs = 0; qs < 2; ++qs)                                            \
      _Pragma("unroll")                                                       \
      for (int t = 0; t < 2; ++t) s[qs][t] = (f32x4){0.f, 0.f, 0.f, 0.f};     \
    _Pragma("unroll")                                                         \
    for (int kb = 0; kb < 4; ++kb) {                                          \
      _Pragma("unroll")                                                       \
      for (int t = 0; t < 2; ++t) {                                           \
        int kcol = wk * 32 + t * 16 + n16;                                    \
        int coff = (kb * 32 + quad * 8) ^ ((kcol & 7) << 3);                  \
        s16x8 bK = *(const s16x8*)(&Kbuf[CUR][kcol * 128 + coff]);            \
        _Pragma("unroll")                                                     \
        for (int qs = 0; qs < 2; ++qs)                                        \
          s[qs][t] = __builtin_amdgcn_mfma_f32_16x16x32_bf16(aQ[qs][kb], bK,  \
                                                             s[qs][t], 0, 0, 0); \
      }                                                                       \
    }                                                                         \
    _Pragma("unroll")                                                         \
    for (int qs = 0; qs < 2; ++qs)                                            \
      _Pragma("unroll")                                                       \
      for (int t = 0; t < 2; ++t)                                             \
        _Pragma("unroll")                                                     \
        for (int r = 0; r < 4; ++r) {                                         \
          float p = __builtin_amdgcn_exp2f(                                   \
              fmaf(s[qs][t][r], 0.28853901f, -17.3123405f));                  \
          l_part[qs][r] += p;                          /* UNmasked denom */   \
          float pv = MC[qs][t][r] ? p : 0.f;           /* dropout */          \
          Ps[wave * 1280 + (qs * 16 + quad * 4 + r) * 40 + t * 16 + n16] = f2bf(pv); \
        }                                                                     \
    s16x8 aP0 = *(const s16x8*)(&Ps[wave * 1280 + n16 * 40 + quad * 8]);      \
    s16x8 aP1 = *(const s16x8*)(&Ps[wave * 1280 + (16 + n16) * 40 + quad * 8]); \
    _Pragma("unroll")                                                         \
    for (int nt = 0; nt < 8; ++nt) {                                          \
      int dv = nt * 16 + n16;                                                 \
      int coff = (wk * 32 + quad * 8) ^ ((dv & 7) << 3);                      \
      s16x8 bV = *(const s16x8*)(&Vbuf[CUR][dv * 64 + coff]);                 \
      o[0][nt] = __builtin_amdgcn_mfma_f32_16x16x32_bf16(aP0, bV, o[0][nt], 0, 0, 0); \
      o[1][nt] = __builtin_amdgcn_mfma_f32_16x16x32_bf16(aP1, bV, o[1][nt], 0, 0, 0); \
    }                                                                         \
    __syncthreads();   /* NXT staging landed (full compute phase) + visible */ \
  }

__global__ __launch_bounds__(256, 2)
void fattn_main(const float* __restrict__ Qg, const u16* __restrict__ Kz,
                const u16* __restrict__ Vz, const int* __restrict__ Mg,
                float* __restrict__ Og)
{
    __shared__ __align__(16) u16 Kbuf[2][64 * 128];   // 32768 B (epilogue: f32 oxch)
    __shared__ __align__(16) u16 Vbuf[2][128 * 64];   // 32768 B
    __shared__ __align__(16) u16 Ps[4 * 32 * 40];     // 10240 B
    __shared__ float lxch[64];                        //   256 B
    // 76032 B total -> 2 blocks/CU (8 waves)

    const int tid  = threadIdx.x;
    const int wave = tid >> 6;
    const int lane = tid & 63;
    const int n16  = lane & 15;
    const int quad = lane >> 4;
    const int wq   = wave & 1;    // q-half: rows wq*32 .. wq*32+31
    const int wk   = wave >> 1;   // k-half: cols wk*32 .. wk*32+31

    // XCD-chunked swizzle (bijective, 512 % 8 == 0)
    const int raw = blockIdx.x;
    const int xcd = raw & 7;
    const int j   = raw >> 3;            // 0..63
    const int b   = xcd * 2 + (j & 1);   // batch
    const int qt  = j >> 1;              // q-tile 0..31
    const int q0  = qt << 6;             // 64 q-rows per block

    // ---- Q fragments straight from global (one-time; no Q LDS) ----
    s16x8 aQ[2][4];
    #pragma unroll
    for (int qs = 0; qs < 2; ++qs) {
        const float* qsrc = Qg + ((size_t)b * SQ_ + q0 + wq * 32 + qs * 16 + n16) * D_;
        #pragma unroll
        for (int kb = 0; kb < 4; ++kb) {
            float4 x = *(const float4*)(qsrc + kb * 32 + quad * 8);
            float4 y = *(const float4*)(qsrc + kb * 32 + quad * 8 + 4);
            u32x4 w = { pk2(x.x, x.y), pk2(x.z, x.w), pk2(y.x, y.y), pk2(y.z, y.w) };
            aQ[qs][kb] = __builtin_bit_cast(s16x8, w);
        }
    }

    f32x4 o[2][8];
    #pragma unroll
    for (int qs = 0; qs < 2; ++qs)
        #pragma unroll
        for (int i = 0; i < 8; ++i) o[qs][i] = (f32x4){0.f, 0.f, 0.f, 0.f};
    float l_part[2][4] = {{0.f, 0.f, 0.f, 0.f}, {0.f, 0.f, 0.f, 0.f}};

    const size_t kvbase = (size_t)b * 262144;   // per-batch slab (u16 elems)
    const int* mbase = Mg + ((size_t)(b * SQ_ + q0 + wq * 32 + quad * 4)) * SK_
                     + wk * 32 + n16;

    // ---- prologue: stage tile 0 (K/V) + tile-0 mask regs ----
    {
        const u16* Kt = Kz + kvbase;
        const u16* Vt = Vz + kvbase;
        #pragma unroll
        for (int i = 0; i < 4; ++i) {
            int c16 = (wave * 4 + i) * 512;
            gload16(&Kbuf[0][c16], &Kt[c16 + lane * 8]);
            gload16(&Vbuf[0][c16], &Vt[c16 + lane * 8]);
        }
    }
    int mA[2][2][4], mB[2][2][4];   // [qsub][t][r]
    #pragma unroll
    for (int qs = 0; qs < 2; ++qs)
        #pragma unroll
        for (int t = 0; t < 2; ++t)
            #pragma unroll
            for (int r = 0; r < 4; ++r)
                mA[qs][t][r] = mbase[(size_t)(qs * 16 + r) * SK_ + t * 16];

    __syncthreads();   // tile 0 staged + visible

    for (int it = 0; it < NT; it += 2) {
        STEP(it,     0, 1, mA, mB)
        STEP(it + 1, 1, 0, mB, mA)
    }

    // ---- epilogue: reduce l across n16 lanes; combine wk halves ----
    float lr[2][4];
    #pragma unroll
    for (int qs = 0; qs < 2; ++qs)
        #pragma unroll
        for (int r = 0; r < 4; ++r) {
            float l = l_part[qs][r];
            #pragma unroll
            for (int off = 1; off < 16; off <<= 1) l += __shfl_xor(l, off);
            lr[qs][r] = l;
        }
    float* oxch = (float*)Kbuf;   // 64 x 128 f32 = 32768 B, exact fit
    if (wk == 1) {
        #pragma unroll
        for (int qs = 0; qs < 2; ++qs)
            #pragma unroll
            for (int r = 0; r < 4; ++r) {
                int row = wq * 32 + qs * 16 + quad * 4 + r;
                #pragma unroll
                for (int nt = 0; nt < 8; ++nt)
                    oxch[row * 128 + nt * 16 + n16] = o[qs][nt][r];
                if (n16 == 0) lxch[row] = lr[qs][r];
            }
    }
    __syncthreads();
    if (wk == 0) {
        const float ksc = 1.0f / 0.9f;
        #pragma unroll
        for (int qs = 0; qs < 2; ++qs)
            #pragma unroll
            for (int r = 0; r < 4; ++r) {
                int row = wq * 32 + qs * 16 + quad * 4 + r;
                float inv = ksc / (lr[qs][r] + lxch[row]);
                size_t ob = ((size_t)b * SQ_ + q0 + row) * (size_t)DV_;
                #pragma unroll
                for (int nt = 0; nt < 8; ++nt)
                    Og[ob + nt * 16 + n16] =
                        (o[qs][nt][r] + oxch[row * 128 + nt * 16 + n16]) * inv;
            }
    }
}

// ---------------- fallback (R4 kernel, used only if workspace too small) ----------------
#define BQ_FB 64
#define LDQ  136
#define LDK  136
#define LDVT 72
#define LDP  72

__global__ __launch_bounds__(256, 2)
void fattn_fb(const float* __restrict__ Qg, const float* __restrict__ Kg,
              const float* __restrict__ Vg, const int* __restrict__ Mg,
              float* __restrict__ Og)
{
    __shared__ u16 Qs[BQ_FB * LDQ];
    __shared__ u16 Ks[BK * LDK];
    __shared__ u16 Vt[DV_ * LDVT];
    __shared__ u16 Ps[4 * 16 * LDP];

    const int tid  = threadIdx.x;
    const int wave = tid >> 6;
    const int lane = tid & 63;
    const int n16  = lane & 15;
    const int quad = lane >> 4;

    const int raw = blockIdx.x;
    const int xcd = raw & 7;
    const int j   = raw >> 3;
    const int b   = xcd * 2 + (j & 1);
    const int q0  = (j >> 1) << 6;

    const int srow = tid >> 4;
    const int scol = (tid & 15) * 8;
    const int vrot = (tid & 7) * 8;

    {
        const float* src = Qg + ((size_t)b * SQ_ + q0) * D_;
        #pragma unroll
        for (int c = 0; c < 4; ++c) {
            int row = c * 16 + srow;
            float4 v0 = *(const float4*)(&src[row * D_ + scol]);
            float4 v1 = *(const float4*)(&src[row * D_ + scol + 4]);
            uint4 pk = { pk2(v0.x, v0.y), pk2(v0.z, v0.w),
                         pk2(v1.x, v1.y), pk2(v1.z, v1.w) };
            *(uint4*)(&Qs[row * LDQ + scol]) = pk;
        }
    }
    __syncthreads();

    s16x8 aQ[4];
    {
        const int qr = wave * 16 + n16;
        #pragma unroll
        for (int kb = 0; kb < 4; ++kb)
            aQ[kb] = *(const s16x8*)(&Qs[qr * LDQ + kb * 32 + quad * 8]);
    }

    f32x4 o[8];
    #pragma unroll
    for (int i = 0; i < 8; ++i) o[i] = (f32x4){0.f, 0.f, 0.f, 0.f};
    float l_part[4] = {0.f, 0.f, 0.f, 0.f};

    const size_t mask_qbase = ((size_t)b * SQ_ + q0 + wave * 16 + quad * 4) * (size_t)SK_;
    const float* baseK = Kg + ((size_t)b * SK_) * D_;
    const float* baseV = Vg + ((size_t)b * SK_) * DV_;

    float4 kf[8], vf[8];
    #pragma unroll
    for (int c = 0; c < 4; ++c) {
        int row = c * 16 + srow;
        kf[2*c]   = *(const float4*)(&baseK[row * D_ + scol]);
        kf[2*c+1] = *(const float4*)(&baseK[row * D_ + scol + 4]);
        vf[2*c]   = *(const float4*)(&baseV[row * DV_ + scol]);
        vf[2*c+1] = *(const float4*)(&baseV[row * DV_ + scol + 4]);
    }
    int mkc[4][4], mkn[4][4];
    #pragma unroll
    for (int t = 0; t < 4; ++t)
        #pragma unroll
        for (int r = 0; r < 4; ++r)
            mkc[t][r] = Mg[mask_qbase + (size_t)r * SK_ + (t * 16 + n16)];

    for (int it = 0; it < NT; ++it) {
        __syncthreads();
        #pragma unroll
        for (int c = 0; c < 4; ++c) {
            int row = c * 16 + srow;
            uint4 pk = { pk2(kf[2*c].x, kf[2*c].y),     pk2(kf[2*c].z, kf[2*c].w),
                         pk2(kf[2*c+1].x, kf[2*c+1].y), pk2(kf[2*c+1].z, kf[2*c+1].w) };
            *(uint4*)(&Ks[row * LDK + scol]) = pk;
        }
        #pragma unroll
        for (int c = 0; c < 4; ++c) {
            int k    = c * 16 + srow;
            int rcol = (k + vrot) & 63;
            int dv0  = scol;
            u32 r0 = pk2(vf[2*c].x,   vf[2*c].y);
            u32 r1 = pk2(vf[2*c].z,   vf[2*c].w);
            u32 r2 = pk2(vf[2*c+1].x, vf[2*c+1].y);
            u32 r3 = pk2(vf[2*c+1].z, vf[2*c+1].w);
            Vt[(dv0 + 0) * LDVT + rcol] = (u16)r0;
            Vt[(dv0 + 1) * LDVT + rcol] = (u16)(r0 >> 16);
            Vt[(dv0 + 2) * LDVT + rcol] = (u16)r1;
            Vt[(dv0 + 3) * LDVT + rcol] = (u16)(r1 >> 16);
            Vt[(dv0 + 4) * LDVT + rcol] = (u16)r2;
            Vt[(dv0 + 5) * LDVT + rcol] = (u16)(r2 >> 16);
            Vt[(dv0 + 6) * LDVT + rcol] = (u16)r3;
            Vt[(dv0 + 7) * LDVT + rcol] = (u16)(r3 >> 16);
        }
        if (it + 1 < NT) {
            const int k0n = (it + 1) * BK;
            #pragma unroll
            for (int c = 0; c < 4; ++c) {
                int row = k0n + c * 16 + srow;
                kf[2*c]   = *(const float4*)(&baseK[row * D_ + scol]);
                kf[2*c+1] = *(const float4*)(&baseK[row * D_ + scol + 4]);
                vf[2*c]   = *(const float4*)(&baseV[row * DV_ + scol]);
                vf[2*c+1] = *(const float4*)(&baseV[row * DV_ + scol + 4]);
            }
            #pragma unroll
            for (int t = 0; t < 4; ++t)
                #pragma unroll
                for (int r = 0; r < 4; ++r)
                    mkn[t][r] = Mg[mask_qbase + (size_t)r * SK_ + (k0n + t * 16 + n16)];
        }
        __syncthreads();

        f32x4 s[4];
        #pragma unroll
        for (int t = 0; t < 4; ++t) s[t] = (f32x4){0.f, 0.f, 0.f, 0.f};
        #pragma unroll
        for (int kb = 0; kb < 4; ++kb) {
            #pragma unroll
            for (int t = 0; t < 4; ++t) {
                s16x8 bK = *(const s16x8*)(&Ks[(t * 16 + n16) * LDK + kb * 32 + quad * 8]);
                s[t] = __builtin_amdgcn_mfma_f32_16x16x32_bf16(aQ[kb], bK, s[t], 0, 0, 0);
            }
        }
        #pragma unroll
        for (int t = 0; t < 4; ++t)
            #pragma unroll
            for (int r = 0; r < 4; ++r) {
                float p = __expf(fmaf(s[t][r], 0.2f, -12.0f));
                l_part[r] += p;
                float pv = mkc[t][r] ? p : 0.f;
                Ps[(wave * 16 + quad * 4 + r) * LDP + t * 16 + n16] = f2bf(pv);
            }
        #pragma unroll
        for (int kk = 0; kk < 2; ++kk) {
            s16x8 aP = *(const s16x8*)(&Ps[(wave * 16 + n16) * LDP + kk * 32 + quad * 8]);
            #pragma unroll
            for (int nt = 0; nt < 8; ++nt) {
                int dv   = nt * 16 + n16;
                int rcol = (kk * 32 + quad * 8 + 8 * ((dv >> 3) & 7)) & 63;
                s16x8 bV = *(const s16x8*)(&Vt[dv * LDVT + rcol]);
                o[nt] = __builtin_amdgcn_mfma_f32_16x16x32_bf16(aP, bV, o[nt], 0, 0, 0);
            }
        }
        #pragma unroll
        for (int t = 0; t < 4; ++t)
            #pragma unroll
            for (int r = 0; r < 4; ++r) mkc[t][r] = mkn[t][r];
    }

    const float keep_scale = 1.0f / 0.9f;
    #pragma unroll
    for (int r = 0; r < 4; ++r) {
        float l = l_part[r];
        #pragma unroll
        for (int off = 1; off < 16; off <<= 1)
            l += __shfl_xor(l, off);
        float inv_l = keep_scale / l;
        size_t obase = ((size_t)b * SQ_ + q0 + wave * 16 + quad * 4 + r) * DV_;
        #pragma unroll
        for (int nt = 0; nt < 8; ++nt)
            Og[obase + nt * 16 + n16] = o[nt][r] * inv_l;
    }
}

extern "C" void kernel_launch(void* const* d_in, const int* in_sizes, int n_in,
                              void* d_out, int out_size, void* d_ws, size_t ws_size,
                              hipStream_t stream) {
    const float* Qg = (const float*)d_in[0];
    const float* Kg = (const float*)d_in[1];
    const float* Vg = (const float*)d_in[2];
    const int*   Mg = (const int*)d_in[3];
    float* Og = (float*)d_out;
    if (d_ws != nullptr && ws_size >= (size_t)16 * 1024 * 1024) {
        u16* Kz = (u16*)d_ws;                   // 8 MB swizzled bf16 K
        u16* Vz = Kz + 4194304;                 // 8 MB transposed+swizzled bf16 V
        prep_k<<<dim3(2048), 256, 0, stream>>>(Kg, Kz);
        prep_v<<<dim3(2048), 256, 0, stream>>>(Vg, Vz);
        fattn_main<<<dim3(512), 256, 0, stream>>>(Qg, Kz, Vz, Mg, Og);
    } else {
        fattn_fb<<<dim3(512), 256, 0, stream>>>(Qg, Kg, Vg, Mg, Og);
    }
}

// Round 11
// 423.846 us; speedup vs baseline: 1.0320x; 1.0320x over previous
//
#include <hip/hip_runtime.h>
#include <stdint.h>

// Fused attention: S=(x1@x2^T)*0.2; P=softmax(S); P=mask?P/0.9:0; O=P@x3
// B=16, SQ=SK=2048, D=DV=128. fp32 in/out, int32 mask, bf16 MFMA compute.
//
// R14 vs R13 (437us: setprio removal cost +18us => setprio HELPS; restored)
// and R8 (418.7us best, main ~124us):
//  PV-LAG PIPELINE: merge the two dependent MFMA phases. Cluster(it) =
//  QK^T(it) + PV(it-1) — 16 ds_reads + 32 MFMAs with independent chains
//  (PV's A operand pA is in regs from last tile's softmax). Halves the
//  serial LDS->MFMA phase transitions per tile (the convoy: 8 phase-locked
//  waves all hitting LDS together then MFMA together — the last unattacked
//  structural element; every pipe <20% busy, setprio's +18us shows issue
//  arbitration at phase boundaries is the sensitivity).
//  - V: single LDS buffer Vs, reg-staged (vr ping-pong, 16 VGPR each);
//    written post-cluster between 2 barriers (A: all PV reads done; B:
//    write visible). Barrier drains proven neutral (R7==R8).
//  - K: gload_lds double-buffer as before (L2-hot Kz).
//  - Epilogue runs the final PV(NT-1). Tile 0 skips PV.
//  - LDS 58.5KB (Kbuf 32K dbuf + Vs 16K + Ps 10K); regs ~145V+64A=209<256.
//  Carried: 64q x 64k / 4 waves; prep_k/prep_v; XCD swizzle; exp2 static-max
//  softmax; cvt_pk; setprio around cluster; cross-wk epilogue via oxch.
//  Fallback (ws < 16MB): R4 kernel.

#define B_   16
#define SQ_  2048
#define SK_  2048
#define D_   128
#define DV_  128
#define BK   64
#define NT   (SK_ / BK)   // 32 tiles

typedef short  s16x8 __attribute__((ext_vector_type(8)));   // MFMA A/B frag
typedef float  f32x4 __attribute__((ext_vector_type(4)));   // MFMA C/D frag
typedef unsigned int u32x4 __attribute__((ext_vector_type(4)));
typedef unsigned short u16;
typedef unsigned int   u32;

// f32 pair -> packed bf16x2, RNE, single instruction (no builtin on gfx950).
__device__ __forceinline__ u32 pk2(float a, float b) {
    u32 r;
    asm("v_cvt_pk_bf16_f32 %0, %1, %2" : "=v"(r) : "v"(a), "v"(b));
    return r;
}
__device__ __forceinline__ u16 f2bf(float f) { return (u16)pk2(f, 0.0f); }

// async global->LDS, 16B per lane. dst = wave-uniform base (HW adds lane*16).
__device__ __forceinline__ void gload16(void* lds, const void* g) {
    __builtin_amdgcn_global_load_lds((const __attribute__((address_space(1))) u32*)g,
                                     (__attribute__((address_space(3))) u32*)lds,
                                     16, 0, 0);
}

// ---------------- pre-pass: K -> bf16, bank-swizzled ----------------
// Kz[b][k][c] with c = col ^ ((k&7)<<3). 8 MB.
__global__ __launch_bounds__(256)
void prep_k(const float* __restrict__ Kg, u16* __restrict__ Kz)
{
    int g   = blockIdx.x * 256 + threadIdx.x;   // 524288 = 16*2048*16
    int b   = g >> 15;
    int rem = g & 32767;
    int k   = rem >> 4;
    int grp = rem & 15;
    const float* src = Kg + ((size_t)b * SK_ + k) * D_ + grp * 8;
    float4 x = *(const float4*)(src);
    float4 y = *(const float4*)(src + 4);
    u32x4 w = { pk2(x.x, x.y), pk2(x.z, x.w), pk2(y.x, y.y), pk2(y.z, y.w) };
    int c = (grp * 8) ^ ((k & 7) << 3);
    *(u32x4*)(&Kz[((size_t)b * SK_ + k) * D_ + c]) = w;
}

// ---------------- pre-pass: V -> transposed bf16 tiles, swizzled ----------------
// Vz[b][kt][dv][c] with c = k_local ^ ((dv&7)<<3); tile = 128x64 bf16 = 16KB.
__global__ __launch_bounds__(256)
void prep_v(const float* __restrict__ Vg, u16* __restrict__ Vz)
{
    int g  = blockIdx.x * 256 + threadIdx.x;    // 524288 = 16*32*8*128
    int dv = g & 127;
    int kg = (g >> 7) & 7;
    int kt = (g >> 10) & 31;
    int b  = g >> 15;
    const float* src = Vg + ((size_t)b * SK_ + kt * 64 + kg * 8) * DV_ + dv;
    float v[8];
    #pragma unroll
    for (int jj = 0; jj < 8; ++jj) v[jj] = src[(size_t)jj * DV_];
    u32x4 w = { pk2(v[0], v[1]), pk2(v[2], v[3]), pk2(v[4], v[5]), pk2(v[6], v[7]) };
    int c = (kg * 8) ^ ((dv & 7) << 3);
    *(u32x4*)(&Vz[(((size_t)b * 32 + kt) * 128 + dv) * 64 + c]) = w;
}

// ---------------- main kernel ----------------
// One tile step. CUR/NXT: K LDS buffers; MC/MN: mask regs; VRC/VRN: V regs.
// pA = P(IT-1) A-frags (regs). Cluster: QK^T(IT) + PV(IT-1).
// exp(0.2*s - 12) == exp2(s*0.28853901 - 17.3123405)
#define STEP(IT, CUR, NXT, MC, MN, VRC, VRN)                                  \
  {                                                                           \
    if ((IT) + 1 < NT) {                                                      \
      /* K staging for IT+1 (async -> LDS) */                                 \
      const u16* Kt = Kz + kvbase + (size_t)((IT) + 1) * 8192;                \
      _Pragma("unroll")                                                       \
      for (int i = 0; i < 4; ++i) {                                           \
        int c16 = (wave * 4 + i) * 512;                                       \
        gload16(&Kbuf[NXT][c16], &Kt[c16 + lane * 8]);                        \
      }                                                                       \
      /* V(IT+1) -> regs (written to Vs next tile) */                         \
      const u16* Vt = Vz + kvbase + (size_t)((IT) + 1) * 8192;                \
      _Pragma("unroll")                                                       \
      for (int jj = 0; jj < 4; ++jj)                                          \
        VRN[jj] = *(const u32x4*)(&Vt[jj * 2048 + tid * 8]);                  \
      /* masks for IT+1 */                                                    \
      _Pragma("unroll")                                                       \
      for (int qs = 0; qs < 2; ++qs)                                          \
        _Pragma("unroll")                                                     \
        for (int t = 0; t < 2; ++t)                                           \
          _Pragma("unroll")                                                   \
          for (int r = 0; r < 4; ++r)                                         \
            MN[qs][t][r] = mbase[(size_t)(qs * 16 + r) * SK_                  \
                                 + ((IT) + 1) * 64 + t * 16];                 \
    }                                                                         \
    f32x4 s[2][2];                                                            \
    _Pragma("unroll")                                                         \
    for (int qs = 0; qs < 2; ++qs)                                            \
      _Pragma("unroll")                                                       \
      for (int t = 0; t < 2; ++t) s[qs][t] = (f32x4){0.f, 0.f, 0.f, 0.f};     \
    __builtin_amdgcn_s_setprio(1);                                            \
    /* merged cluster: QK^T(IT) + PV(IT-1) — independent chains */            \
    _Pragma("unroll")                                                         \
    for (int kb = 0; kb < 4; ++kb) {                                          \
      _Pragma("unroll")                                                       \
      for (int t = 0; t < 2; ++t) {                                           \
        int kcol = wk * 32 + t * 16 + n16;                                    \
        int coff = (kb * 32 + quad * 8) ^ ((kcol & 7) << 3);                  \
        s16x8 bK = *(const s16x8*)(&Kbuf[CUR][kcol * 128 + coff]);            \
        _Pragma("unroll")                                                     \
        for (int qs = 0; qs < 2; ++qs)                                        \
          s[qs][t] = __builtin_amdgcn_mfma_f32_16x16x32_bf16(aQ[qs][kb], bK,  \
                                                             s[qs][t], 0, 0, 0); \
      }                                                                       \
    }                                                                         \
    if ((IT) > 0) {                                                           \
      _Pragma("unroll")                                                       \
      for (int nt = 0; nt < 8; ++nt) {                                        \
        int dv = nt * 16 + n16;                                               \
        int coff = (wk * 32 + quad * 8) ^ ((dv & 7) << 3);                    \
        s16x8 bV = *(const s16x8*)(&Vs[dv * 64 + coff]);                      \
        o[0][nt] = __builtin_amdgcn_mfma_f32_16x16x32_bf16(pA0, bV, o[0][nt], 0, 0, 0); \
        o[1][nt] = __builtin_amdgcn_mfma_f32_16x16x32_bf16(pA1, bV, o[1][nt], 0, 0, 0); \
      }                                                                       \
    }                                                                         \
    __builtin_amdgcn_s_setprio(0);                                            \
    /* softmax(IT) -> Ps -> new pA */                                         \
    _Pragma("unroll")                                                         \
    for (int qs = 0; qs < 2; ++qs)                                            \
      _Pragma("unroll")                                                       \
      for (int t = 0; t < 2; ++t)                                             \
        _Pragma("unroll")                                                     \
        for (int r = 0; r < 4; ++r) {                                         \
          float p = __builtin_amdgcn_exp2f(                                   \
              fmaf(s[qs][t][r], 0.28853901f, -17.3123405f));                  \
          l_part[qs][r] += p;                          /* UNmasked denom */   \
          float pv = MC[qs][t][r] ? p : 0.f;           /* dropout */          \
          Ps[wave * 1280 + (qs * 16 + quad * 4 + r) * 40 + t * 16 + n16] = f2bf(pv); \
        }                                                                     \
    pA0 = *(const s16x8*)(&Ps[wave * 1280 + n16 * 40 + quad * 8]);            \
    pA1 = *(const s16x8*)(&Ps[wave * 1280 + (16 + n16) * 40 + quad * 8]);     \
    __syncthreads();   /* A: all waves' PV reads of Vs done */                \
    _Pragma("unroll")                                                         \
    for (int jj = 0; jj < 4; ++jj)                                            \
      *(u32x4*)(&Vs[jj * 2048 + tid * 8]) = VRC[jj];   /* Vs <= V(IT) */      \
    __syncthreads();   /* B: Vs visible; Kbuf[NXT] staged (A drained vm) */   \
  }

__global__ __launch_bounds__(256, 2)
void fattn_main(const float* __restrict__ Qg, const u16* __restrict__ Kz,
                const u16* __restrict__ Vz, const int* __restrict__ Mg,
                float* __restrict__ Og)
{
    __shared__ __align__(16) u16 Kbuf[2][64 * 128];   // 32768 B (epilogue: f32 oxch)
    __shared__ __align__(16) u16 Vs[128 * 64];        // 16384 B (single, reg-staged)
    __shared__ __align__(16) u16 Ps[4 * 32 * 40];     // 10240 B
    __shared__ float lxch[64];                        //   256 B
    // 59648 B total -> 2 blocks/CU (8 waves)

    const int tid  = threadIdx.x;
    const int wave = tid >> 6;
    const int lane = tid & 63;
    const int n16  = lane & 15;
    const int quad = lane >> 4;
    const int wq   = wave & 1;    // q-half: rows wq*32 .. wq*32+31
    const int wk   = wave >> 1;   // k-half: cols wk*32 .. wk*32+31

    // XCD-chunked swizzle (bijective, 512 % 8 == 0)
    const int raw = blockIdx.x;
    const int xcd = raw & 7;
    const int j   = raw >> 3;            // 0..63
    const int b   = xcd * 2 + (j & 1);   // batch
    const int qt  = j >> 1;              // q-tile 0..31
    const int q0  = qt << 6;             // 64 q-rows per block

    // ---- Q fragments straight from global (one-time; no Q LDS) ----
    s16x8 aQ[2][4];
    #pragma unroll
    for (int qs = 0; qs < 2; ++qs) {
        const float* qsrc = Qg + ((size_t)b * SQ_ + q0 + wq * 32 + qs * 16 + n16) * D_;
        #pragma unroll
        for (int kb = 0; kb < 4; ++kb) {
            float4 x = *(const float4*)(qsrc + kb * 32 + quad * 8);
            float4 y = *(const float4*)(qsrc + kb * 32 + quad * 8 + 4);
            u32x4 w = { pk2(x.x, x.y), pk2(x.z, x.w), pk2(y.x, y.y), pk2(y.z, y.w) };
            aQ[qs][kb] = __builtin_bit_cast(s16x8, w);
        }
    }

    f32x4 o[2][8];
    #pragma unroll
    for (int qs = 0; qs < 2; ++qs)
        #pragma unroll
        for (int i = 0; i < 8; ++i) o[qs][i] = (f32x4){0.f, 0.f, 0.f, 0.f};
    float l_part[2][4] = {{0.f, 0.f, 0.f, 0.f}, {0.f, 0.f, 0.f, 0.f}};
    s16x8 pA0 = (s16x8){0,0,0,0,0,0,0,0};
    s16x8 pA1 = (s16x8){0,0,0,0,0,0,0,0};

    const size_t kvbase = (size_t)b * 262144;   // per-batch slab (u16 elems)
    const int* mbase = Mg + ((size_t)(b * SQ_ + q0 + wq * 32 + quad * 4)) * SK_
                     + wk * 32 + n16;

    // ---- prologue: K(0) -> Kbuf[0], V(0) -> vrA regs, mask(0) -> mA ----
    {
        const u16* Kt = Kz + kvbase;
        #pragma unroll
        for (int i = 0; i < 4; ++i) {
            int c16 = (wave * 4 + i) * 512;
            gload16(&Kbuf[0][c16], &Kt[c16 + lane * 8]);
        }
    }
    u32x4 vrA[4], vrB[4];
    {
        const u16* Vt = Vz + kvbase;
        #pragma unroll
        for (int jj = 0; jj < 4; ++jj)
            vrA[jj] = *(const u32x4*)(&Vt[jj * 2048 + tid * 8]);
    }
    int mA[2][2][4], mB[2][2][4];   // [qsub][t][r]
    #pragma unroll
    for (int qs = 0; qs < 2; ++qs)
        #pragma unroll
        for (int t = 0; t < 2; ++t)
            #pragma unroll
            for (int r = 0; r < 4; ++r)
                mA[qs][t][r] = mbase[(size_t)(qs * 16 + r) * SK_ + t * 16];

    __syncthreads();   // tile 0 K staged + visible

    for (int it = 0; it < NT; it += 2) {
        STEP(it,     0, 1, mA, mB, vrA, vrB)
        STEP(it + 1, 1, 0, mB, mA, vrB, vrA)
    }

    // ---- final PV(NT-1): pA = P(31), Vs = V(31) ----
    #pragma unroll
    for (int nt = 0; nt < 8; ++nt) {
        int dv = nt * 16 + n16;
        int coff = (wk * 32 + quad * 8) ^ ((dv & 7) << 3);
        s16x8 bV = *(const s16x8*)(&Vs[dv * 64 + coff]);
        o[0][nt] = __builtin_amdgcn_mfma_f32_16x16x32_bf16(pA0, bV, o[0][nt], 0, 0, 0);
        o[1][nt] = __builtin_amdgcn_mfma_f32_16x16x32_bf16(pA1, bV, o[1][nt], 0, 0, 0);
    }

    // ---- epilogue: reduce l across n16 lanes; combine wk halves ----
    float lr[2][4];
    #pragma unroll
    for (int qs = 0; qs < 2; ++qs)
        #pragma unroll
        for (int r = 0; r < 4; ++r) {
            float l = l_part[qs][r];
            #pragma unroll
            for (int off = 1; off < 16; off <<= 1) l += __shfl_xor(l, off);
            lr[qs][r] = l;
        }
    float* oxch = (float*)Kbuf;   // 64 x 128 f32 = 32768 B, exact fit
    __syncthreads();   // all waves done with Kbuf/Vs before overlay
    if (wk == 1) {
        #pragma unroll
        for (int qs = 0; qs < 2; ++qs)
            #pragma unroll
            for (int r = 0; r < 4; ++r) {
                int row = wq * 32 + qs * 16 + quad * 4 + r;
                #pragma unroll
                for (int nt = 0; nt < 8; ++nt)
                    oxch[row * 128 + nt * 16 + n16] = o[qs][nt][r];
                if (n16 == 0) lxch[row] = lr[qs][r];
            }
    }
    __syncthreads();
    if (wk == 0) {
        const float ksc = 1.0f / 0.9f;
        #pragma unroll
        for (int qs = 0; qs < 2; ++qs)
            #pragma unroll
            for (int r = 0; r < 4; ++r) {
                int row = wq * 32 + qs * 16 + quad * 4 + r;
                float inv = ksc / (lr[qs][r] + lxch[row]);
                size_t ob = ((size_t)b * SQ_ + q0 + row) * (size_t)DV_;
                #pragma unroll
                for (int nt = 0; nt < 8; ++nt)
                    Og[ob + nt * 16 + n16] =
                        (o[qs][nt][r] + oxch[row * 128 + nt * 16 + n16]) * inv;
            }
    }
}

// ---------------- fallback (R4 kernel, used only if workspace too small) ----------------
#define BQ_FB 64
#define LDQ  136
#define LDK  136
#define LDVT 72
#define LDP  72

__global__ __launch_bounds__(256, 2)
void fattn_fb(const float* __restrict__ Qg, const float* __restrict__ Kg,
              const float* __restrict__ Vg, const int* __restrict__ Mg,
              float* __restrict__ Og)
{
    __shared__ u16 Qs[BQ_FB * LDQ];
    __shared__ u16 Ks[BK * LDK];
    __shared__ u16 Vt[DV_ * LDVT];
    __shared__ u16 Ps[4 * 16 * LDP];

    const int tid  = threadIdx.x;
    const int wave = tid >> 6;
    const int lane = tid & 63;
    const int n16  = lane & 15;
    const int quad = lane >> 4;

    const int raw = blockIdx.x;
    const int xcd = raw & 7;
    const int j   = raw >> 3;
    const int b   = xcd * 2 + (j & 1);
    const int q0  = (j >> 1) << 6;

    const int srow = tid >> 4;
    const int scol = (tid & 15) * 8;
    const int vrot = (tid & 7) * 8;

    {
        const float* src = Qg + ((size_t)b * SQ_ + q0) * D_;
        #pragma unroll
        for (int c = 0; c < 4; ++c) {
            int row = c * 16 + srow;
            float4 v0 = *(const float4*)(&src[row * D_ + scol]);
            float4 v1 = *(const float4*)(&src[row * D_ + scol + 4]);
            uint4 pk = { pk2(v0.x, v0.y), pk2(v0.z, v0.w),
                         pk2(v1.x, v1.y), pk2(v1.z, v1.w) };
            *(uint4*)(&Qs[row * LDQ + scol]) = pk;
        }
    }
    __syncthreads();

    s16x8 aQ[4];
    {
        const int qr = wave * 16 + n16;
        #pragma unroll
        for (int kb = 0; kb < 4; ++kb)
            aQ[kb] = *(const s16x8*)(&Qs[qr * LDQ + kb * 32 + quad * 8]);
    }

    f32x4 o[8];
    #pragma unroll
    for (int i = 0; i < 8; ++i) o[i] = (f32x4){0.f, 0.f, 0.f, 0.f};
    float l_part[4] = {0.f, 0.f, 0.f, 0.f};

    const size_t mask_qbase = ((size_t)b * SQ_ + q0 + wave * 16 + quad * 4) * (size_t)SK_;
    const float* baseK = Kg + ((size_t)b * SK_) * D_;
    const float* baseV = Vg + ((size_t)b * SK_) * DV_;

    float4 kf[8], vf[8];
    #pragma unroll
    for (int c = 0; c < 4; ++c) {
        int row = c * 16 + srow;
        kf[2*c]   = *(const float4*)(&baseK[row * D_ + scol]);
        kf[2*c+1] = *(const float4*)(&baseK[row * D_ + scol + 4]);
        vf[2*c]   = *(const float4*)(&baseV[row * DV_ + scol]);
        vf[2*c+1] = *(const float4*)(&baseV[row * DV_ + scol + 4]);
    }
    int mkc[4][4], mkn[4][4];
    #pragma unroll
    for (int t = 0; t < 4; ++t)
        #pragma unroll
        for (int r = 0; r < 4; ++r)
            mkc[t][r] = Mg[mask_qbase + (size_t)r * SK_ + (t * 16 + n16)];

    for (int it = 0; it < NT; ++it) {
        __syncthreads();
        #pragma unroll
        for (int c = 0; c < 4; ++c) {
            int row = c * 16 + srow;
            uint4 pk = { pk2(kf[2*c].x, kf[2*c].y),     pk2(kf[2*c].z, kf[2*c].w),
                         pk2(kf[2*c+1].x, kf[2*c+1].y), pk2(kf[2*c+1].z, kf[2*c+1].w) };
            *(uint4*)(&Ks[row * LDK + scol]) = pk;
        }
        #pragma unroll
        for (int c = 0; c < 4; ++c) {
            int k    = c * 16 + srow;
            int rcol = (k + vrot) & 63;
            int dv0  = scol;
            u32 r0 = pk2(vf[2*c].x,   vf[2*c].y);
            u32 r1 = pk2(vf[2*c].z,   vf[2*c].w);
            u32 r2 = pk2(vf[2*c+1].x, vf[2*c+1].y);
            u32 r3 = pk2(vf[2*c+1].z, vf[2*c+1].w);
            Vt[(dv0 + 0) * LDVT + rcol] = (u16)r0;
            Vt[(dv0 + 1) * LDVT + rcol] = (u16)(r0 >> 16);
            Vt[(dv0 + 2) * LDVT + rcol] = (u16)r1;
            Vt[(dv0 + 3) * LDVT + rcol] = (u16)(r1 >> 16);
            Vt[(dv0 + 4) * LDVT + rcol] = (u16)r2;
            Vt[(dv0 + 5) * LDVT + rcol] = (u16)(r2 >> 16);
            Vt[(dv0 + 6) * LDVT + rcol] = (u16)r3;
            Vt[(dv0 + 7) * LDVT + rcol] = (u16)(r3 >> 16);
        }
        if (it + 1 < NT) {
            const int k0n = (it + 1) * BK;
            #pragma unroll
            for (int c = 0; c < 4; ++c) {
                int row = k0n + c * 16 + srow;
                kf[2*c]   = *(const float4*)(&baseK[row * D_ + scol]);
                kf[2*c+1] = *(const float4*)(&baseK[row * D_ + scol + 4]);
                vf[2*c]   = *(const float4*)(&baseV[row * DV_ + scol]);
                vf[2*c+1] = *(const float4*)(&baseV[row * DV_ + scol + 4]);
            }
            #pragma unroll
            for (int t = 0; t < 4; ++t)
                #pragma unroll
                for (int r = 0; r < 4; ++r)
                    mkn[t][r] = Mg[mask_qbase + (size_t)r * SK_ + (k0n + t * 16 + n16)];
        }
        __syncthreads();

        f32x4 s[4];
        #pragma unroll
        for (int t = 0; t < 4; ++t) s[t] = (f32x4){0.f, 0.f, 0.f, 0.f};
        #pragma unroll
        for (int kb = 0; kb < 4; ++kb) {
            #pragma unroll
            for (int t = 0; t < 4; ++t) {
                s16x8 bK = *(const s16x8*)(&Ks[(t * 16 + n16) * LDK + kb * 32 + quad * 8]);
                s[t] = __builtin_amdgcn_mfma_f32_16x16x32_bf16(aQ[kb], bK, s[t], 0, 0, 0);
            }
        }
        #pragma unroll
        for (int t = 0; t < 4; ++t)
            #pragma unroll
            for (int r = 0; r < 4; ++r) {
                float p = __expf(fmaf(s[t][r], 0.2f, -12.0f));
                l_part[r] += p;
                float pv = mkc[t][r] ? p : 0.f;
                Ps[(wave * 16 + quad * 4 + r) * LDP + t * 16 + n16] = f2bf(pv);
            }
        #pragma unroll
        for (int kk = 0; kk < 2; ++kk) {
            s16x8 aP = *(const s16x8*)(&Ps[(wave * 16 + n16) * LDP + kk * 32 + quad * 8]);
            #pragma unroll
            for (int nt = 0; nt < 8; ++nt) {
                int dv   = nt * 16 + n16;
                int rcol = (kk * 32 + quad * 8 + 8 * ((dv >> 3) & 7)) & 63;
                s16x8 bV = *(const s16x8*)(&Vt[dv * LDVT + rcol]);
                o[nt] = __builtin_amdgcn_mfma_f32_16x16x32_bf16(aP, bV, o[nt], 0, 0, 0);
            }
        }
        #pragma unroll
        for (int t = 0; t < 4; ++t)
            #pragma unroll
            for (int r = 0; r < 4; ++r) mkc[t][r] = mkn[t][r];
    }

    const float keep_scale = 1.0f / 0.9f;
    #pragma unroll
    for (int r = 0; r < 4; ++r) {
        float l = l_part[r];
        #pragma unroll
        for (int off = 1; off < 16; off <<= 1)
            l += __shfl_xor(l, off);
        float inv_l = keep_scale / l;
        size_t obase = ((size_t)b * SQ_ + q0 + wave * 16 + quad * 4 + r) * DV_;
        #pragma unroll
        for (int nt = 0; nt < 8; ++nt)
            Og[obase + nt * 16 + n16] = o[nt][r] * inv_l;
    }
}

extern "C" void kernel_launch(void* const* d_in, const int* in_sizes, int n_in,
                              void* d_out, int out_size, void* d_ws, size_t ws_size,
                              hipStream_t stream) {
    const float* Qg = (const float*)d_in[0];
    const float* Kg = (const float*)d_in[1];
    const float* Vg = (const float*)d_in[2];
    const int*   Mg = (const int*)d_in[3];
    float* Og = (float*)d_out;
    if (d_ws != nullptr && ws_size >= (size_t)16 * 1024 * 1024) {
        u16* Kz = (u16*)d_ws;                   // 8 MB swizzled bf16 K
        u16* Vz = Kz + 4194304;                 // 8 MB transposed+swizzled bf16 V
        prep_k<<<dim3(2048), 256, 0, stream>>>(Kg, Kz);
        prep_v<<<dim3(2048), 256, 0, stream>>>(Vg, Vz);
        fattn_main<<<dim3(512), 256, 0, stream>>>(Qg, Kz, Vz, Mg, Og);
    } else {
        fattn_fb<<<dim3(512), 256, 0, stream>>>(Qg, Kg, Vg, Mg, Og);
    }
}

// Round 12
// 418.300 us; speedup vs baseline: 1.0457x; 1.0133x over previous
//
#include <hip/hip_runtime.h>
#include <stdint.h>

// Fused attention: S=(x1@x2^T)*0.2; P=softmax(S); P=mask?P/0.9:0; O=P@x3
// B=16, SQ=SK=2048, D=DV=128. fp32 in/out, int32 mask, bf16 MFMA compute.
//
// R15 = R8 restored verbatim (session best: 418.7us). R14's PV-lag pipeline
// was neutral-to-negative (423.8) -> reverted. Session ledger: best total
// 418.7 = ~119 fixed harness + ~160 unavoidable 1GB ws re-poison fill +
// ~16 preps + ~124 main. Falsified by measurement: HBM BW, XCD/L2 locality
// beyond current swizzle, occupancy (2->4 blk/CU no change), barrier drain
// (counted vmcnt neutral), LDS-pipe throughput (K-in-regs worse both ways),
// mask-stream decoupling (prep_m net worse), barrier-free loop (VGPR spill),
// setprio removal (-18us: it HELPS), PV-lag phase merge (neutral). Main is
// latency-plateaued with all pipes <20% busy. Load-bearing wins: bf16 +
// XOR-swizzled global K/V layouts via pre-passes (main 170->124us) and
// s_setprio around MFMA clusters.
//
// Structure (R8): 64q x 64k block, 4 waves (32q x 32k each), grid 512 =
// 2 blocks/CU; K/V LDS double-buffer via XOR-swizzled Kz/Vz global layouts +
// linear global_load_lds dest (rule #21); counted-vmcnt tile barrier
// (s_waitcnt vmcnt(16) + s_barrier; gloads pinned oldest via sched_barrier);
// in-loop coalesced mask dword loads ping-ponged one tile ahead; exp2
// static-max softmax p=exp2(s*0.28853901-17.3123405) (shift cancels in
// 1/sum); XCD-chunked swizzle; v_cvt_pk_bf16_f32 packing; cross-wk epilogue
// combine via oxch. Fallback (ws < 16MB): R4 kernel.

#define B_   16
#define SQ_  2048
#define SK_  2048
#define D_   128
#define DV_  128
#define BK   64
#define NT   (SK_ / BK)   // 32 tiles

typedef short  s16x8 __attribute__((ext_vector_type(8)));   // MFMA A/B frag
typedef float  f32x4 __attribute__((ext_vector_type(4)));   // MFMA C/D frag
typedef unsigned int u32x4 __attribute__((ext_vector_type(4)));
typedef unsigned short u16;
typedef unsigned int   u32;

// f32 pair -> packed bf16x2, RNE, single instruction (no builtin on gfx950).
__device__ __forceinline__ u32 pk2(float a, float b) {
    u32 r;
    asm("v_cvt_pk_bf16_f32 %0, %1, %2" : "=v"(r) : "v"(a), "v"(b));
    return r;
}
__device__ __forceinline__ u16 f2bf(float f) { return (u16)pk2(f, 0.0f); }

// async global->LDS, 16B per lane. dst = wave-uniform base (HW adds lane*16),
// src = per-lane address.
__device__ __forceinline__ void gload16(void* lds, const void* g) {
    __builtin_amdgcn_global_load_lds((const __attribute__((address_space(1))) u32*)g,
                                     (__attribute__((address_space(3))) u32*)lds,
                                     16, 0, 0);
}

// ---------------- pre-pass: K -> bf16, bank-swizzled ----------------
// Kz[b][k][c] with c = col ^ ((k&7)<<3). 8 MB.
__global__ __launch_bounds__(256)
void prep_k(const float* __restrict__ Kg, u16* __restrict__ Kz)
{
    int g   = blockIdx.x * 256 + threadIdx.x;   // 524288 = 16*2048*16
    int b   = g >> 15;
    int rem = g & 32767;
    int k   = rem >> 4;
    int grp = rem & 15;
    const float* src = Kg + ((size_t)b * SK_ + k) * D_ + grp * 8;
    float4 x = *(const float4*)(src);
    float4 y = *(const float4*)(src + 4);
    u32x4 w = { pk2(x.x, x.y), pk2(x.z, x.w), pk2(y.x, y.y), pk2(y.z, y.w) };
    int c = (grp * 8) ^ ((k & 7) << 3);
    *(u32x4*)(&Kz[((size_t)b * SK_ + k) * D_ + c]) = w;
}

// ---------------- pre-pass: V -> transposed bf16 tiles, swizzled ----------------
// Vz[b][kt][dv][c] with c = k_local ^ ((dv&7)<<3); tile = 128x64 bf16 = 16KB.
// dv is lane-fastest -> each load instr covers 4 full 64B lines.
__global__ __launch_bounds__(256)
void prep_v(const float* __restrict__ Vg, u16* __restrict__ Vz)
{
    int g  = blockIdx.x * 256 + threadIdx.x;    // 524288 = 16*32*8*128
    int dv = g & 127;
    int kg = (g >> 7) & 7;
    int kt = (g >> 10) & 31;
    int b  = g >> 15;
    const float* src = Vg + ((size_t)b * SK_ + kt * 64 + kg * 8) * DV_ + dv;
    float v[8];
    #pragma unroll
    for (int jj = 0; jj < 8; ++jj) v[jj] = src[(size_t)jj * DV_];
    u32x4 w = { pk2(v[0], v[1]), pk2(v[2], v[3]), pk2(v[4], v[5]), pk2(v[6], v[7]) };
    int c = (kg * 8) ^ ((dv & 7) << 3);
    *(u32x4*)(&Vz[(((size_t)b * 32 + kt) * 128 + dv) * 64 + c]) = w;
}

// ---------------- main kernel ----------------
// One tile step. CUR/NXT: LDS buffer indices; MC/MN: mask reg ping-pong.
// exp(0.2*s - 12) == exp2(s*0.28853901 - 17.3123405)
#define STEP(IT, CUR, NXT, MC, MN)                                            \
  {                                                                           \
    if ((IT) + 1 < NT) {   /* staging for t+1: these must be OLDEST vmem */   \
      const u16* Kt = Kz + kvbase + (size_t)((IT) + 1) * 8192;                \
      const u16* Vt = Vz + kvbase + (size_t)((IT) + 1) * 8192;                \
      _Pragma("unroll")                                                       \
      for (int i = 0; i < 4; ++i) {                                           \
        int c16 = (wave * 4 + i) * 512;                                       \
        gload16(&Kbuf[NXT][c16], &Kt[c16 + lane * 8]);                        \
        gload16(&Vbuf[NXT][c16], &Vt[c16 + lane * 8]);                        \
      }                                                                       \
    }                                                                         \
    __builtin_amdgcn_sched_barrier(0);  /* pin: gloads before mask loads */   \
    if ((IT) + 1 < NT) {   /* mask for t+1: may stay in flight past barrier */\
      _Pragma("unroll")                                                       \
      for (int qs = 0; qs < 2; ++qs)                                          \
        _Pragma("unroll")                                                     \
        for (int t = 0; t < 2; ++t)                                           \
          _Pragma("unroll")                                                   \
          for (int r = 0; r < 4; ++r)                                         \
            MN[qs][t][r] = mbase[(size_t)(qs * 16 + r) * SK_                  \
                                 + ((IT) + 1) * 64 + t * 16];                 \
    }                                                                         \
    f32x4 s[2][2];                                                            \
    _Pragma("unroll")                                                         \
    for (int qs = 0; qs < 2; ++qs)                                            \
      _Pragma("unroll")                                                       \
      for (int t = 0; t < 2; ++t) s[qs][t] = (f32x4){0.f, 0.f, 0.f, 0.f};     \
    __builtin_amdgcn_s_setprio(1);                                            \
    _Pragma("unroll")                                                         \
    for (int kb = 0; kb < 4; ++kb) {                                          \
      _Pragma("unroll")                                                       \
      for (int t = 0; t < 2; ++t) {                                           \
        int kcol = wk * 32 + t * 16 + n16;                                    \
        int coff = (kb * 32 + quad * 8) ^ ((kcol & 7) << 3);                  \
        s16x8 bK = *(const s16x8*)(&Kbuf[CUR][kcol * 128 + coff]);            \
        _Pragma("unroll")                                                     \
        for (int qs = 0; qs < 2; ++qs)                                        \
          s[qs][t] = __builtin_amdgcn_mfma_f32_16x16x32_bf16(aQ[qs][kb], bK,  \
                                                             s[qs][t], 0, 0, 0); \
      }                                                                       \
    }                                                                         \
    __builtin_amdgcn_s_setprio(0);                                            \
    _Pragma("unroll")                                                         \
    for (int qs = 0; qs < 2; ++qs)                                            \
      _Pragma("unroll")                                                       \
      for (int t = 0; t < 2; ++t)                                             \
        _Pragma("unroll")                                                     \
        for (int r = 0; r < 4; ++r) {                                         \
          float p = __builtin_amdgcn_exp2f(                                   \
              fmaf(s[qs][t][r], 0.28853901f, -17.3123405f));                  \
          l_part[qs][r] += p;                          /* UNmasked denom */   \
          float pv = MC[qs][t][r] ? p : 0.f;           /* dropout */          \
          Ps[wave * 1280 + (qs * 16 + quad * 4 + r) * 40 + t * 16 + n16] =    \
              f2bf(pv);                                                       \
        }                                                                     \
    s16x8 aP0 = *(const s16x8*)(&Ps[wave * 1280 + n16 * 40 + quad * 8]);      \
    s16x8 aP1 = *(const s16x8*)(&Ps[wave * 1280 + (16 + n16) * 40 + quad * 8]); \
    __builtin_amdgcn_s_setprio(1);                                            \
    _Pragma("unroll")                                                         \
    for (int nt = 0; nt < 8; ++nt) {                                          \
      int dv = nt * 16 + n16;                                                 \
      int coff = (wk * 32 + quad * 8) ^ ((dv & 7) << 3);                      \
      s16x8 bV = *(const s16x8*)(&Vbuf[CUR][dv * 64 + coff]);                 \
      o[0][nt] = __builtin_amdgcn_mfma_f32_16x16x32_bf16(aP0, bV, o[0][nt], 0, 0, 0); \
      o[1][nt] = __builtin_amdgcn_mfma_f32_16x16x32_bf16(aP1, bV, o[1][nt], 0, 0, 0); \
    }                                                                         \
    __builtin_amdgcn_s_setprio(0);                                            \
    /* counted drain: 8 gloads (oldest) done; 16 mask loads may remain */     \
    asm volatile("s_waitcnt vmcnt(16)" ::: "memory");                         \
    __builtin_amdgcn_s_barrier();                                             \
    __builtin_amdgcn_sched_barrier(0);                                        \
  }

__global__ __launch_bounds__(256, 2)
void fattn_main(const float* __restrict__ Qg, const u16* __restrict__ Kz,
                const u16* __restrict__ Vz, const int* __restrict__ Mg,
                float* __restrict__ Og)
{
    __shared__ __align__(16) u16 Kbuf[2][64 * 128];   // 32768 B (epilogue: f32 oxch)
    __shared__ __align__(16) u16 Vbuf[2][128 * 64];   // 32768 B
    __shared__ __align__(16) u16 Ps[4 * 32 * 40];     // 10240 B (per-wave 32x32, stride 40)
    __shared__ float lxch[64];                        //   256 B
    // 76032 B total -> 2 blocks/CU (8 waves)

    const int tid  = threadIdx.x;
    const int wave = tid >> 6;
    const int lane = tid & 63;
    const int n16  = lane & 15;
    const int quad = lane >> 4;
    const int wq   = wave & 1;    // q-half: rows wq*32 .. wq*32+31
    const int wk   = wave >> 1;   // k-half: cols wk*32 .. wk*32+31

    // XCD-chunked swizzle (bijective, 512 % 8 == 0): XCD x owns batches
    // {2x,2x+1}; the two co-resident blocks of a CU share a batch.
    const int raw = blockIdx.x;
    const int xcd = raw & 7;
    const int j   = raw >> 3;            // 0..63
    const int b   = xcd * 2 + (j & 1);   // batch
    const int qt  = j >> 1;              // q-tile 0..31
    const int q0  = qt << 6;             // 64 q-rows per block

    // ---- Q fragments straight from global (one-time; no Q LDS) ----
    s16x8 aQ[2][4];
    #pragma unroll
    for (int qs = 0; qs < 2; ++qs) {
        const float* qsrc = Qg + ((size_t)b * SQ_ + q0 + wq * 32 + qs * 16 + n16) * D_;
        #pragma unroll
        for (int kb = 0; kb < 4; ++kb) {
            float4 x = *(const float4*)(qsrc + kb * 32 + quad * 8);
            float4 y = *(const float4*)(qsrc + kb * 32 + quad * 8 + 4);
            u32x4 w = { pk2(x.x, x.y), pk2(x.z, x.w), pk2(y.x, y.y), pk2(y.z, y.w) };
            aQ[qs][kb] = __builtin_bit_cast(s16x8, w);
        }
    }

    f32x4 o[2][8];
    #pragma unroll
    for (int qs = 0; qs < 2; ++qs)
        #pragma unroll
        for (int i = 0; i < 8; ++i) o[qs][i] = (f32x4){0.f, 0.f, 0.f, 0.f};
    float l_part[2][4] = {{0.f, 0.f, 0.f, 0.f}, {0.f, 0.f, 0.f, 0.f}};

    const size_t kvbase = (size_t)b * 262144;   // per-batch slab (u16 elems)

    // mask base: row (b,q0+wq*32+quad*4), col wk*32+n16
    const int* mbase = Mg + ((size_t)(b * SQ_ + q0 + wq * 32 + quad * 4)) * SK_
                     + wk * 32 + n16;

    // ---- prologue: stage tile 0 (K/V) + tile-0 mask regs ----
    {
        const u16* Kt = Kz + kvbase;
        const u16* Vt = Vz + kvbase;
        #pragma unroll
        for (int i = 0; i < 4; ++i) {
            int c16 = (wave * 4 + i) * 512;
            gload16(&Kbuf[0][c16], &Kt[c16 + lane * 8]);
            gload16(&Vbuf[0][c16], &Vt[c16 + lane * 8]);
        }
    }
    int mA[2][2][4], mB[2][2][4];   // [qsub][t][r]
    #pragma unroll
    for (int qs = 0; qs < 2; ++qs)
        #pragma unroll
        for (int t = 0; t < 2; ++t)
            #pragma unroll
            for (int r = 0; r < 4; ++r)
                mA[qs][t][r] = mbase[(size_t)(qs * 16 + r) * SK_ + t * 16];

    __syncthreads();   // tile 0 staged + visible (full drain, one-time)

    for (int it = 0; it < NT; it += 2) {
        STEP(it,     0, 1, mA, mB)
        STEP(it + 1, 1, 0, mB, mA)
    }

    // ---- epilogue: reduce l across n16 lanes; combine wk halves ----
    float lr[2][4];
    #pragma unroll
    for (int qs = 0; qs < 2; ++qs)
        #pragma unroll
        for (int r = 0; r < 4; ++r) {
            float l = l_part[qs][r];
            #pragma unroll
            for (int off = 1; off < 16; off <<= 1) l += __shfl_xor(l, off);
            lr[qs][r] = l;
        }
    float* oxch = (float*)Kbuf;   // 64 x 128 f32 = 32768 B, exact fit
    if (wk == 1) {
        #pragma unroll
        for (int qs = 0; qs < 2; ++qs)
            #pragma unroll
            for (int r = 0; r < 4; ++r) {
                int row = wq * 32 + qs * 16 + quad * 4 + r;
                #pragma unroll
                for (int nt = 0; nt < 8; ++nt)
                    oxch[row * 128 + nt * 16 + n16] = o[qs][nt][r];
                if (n16 == 0) lxch[row] = lr[qs][r];
            }
    }
    __syncthreads();
    if (wk == 0) {
        const float ksc = 1.0f / 0.9f;
        #pragma unroll
        for (int qs = 0; qs < 2; ++qs)
            #pragma unroll
            for (int r = 0; r < 4; ++r) {
                int row = wq * 32 + qs * 16 + quad * 4 + r;
                float inv = ksc / (lr[qs][r] + lxch[row]);
                size_t ob = ((size_t)b * SQ_ + q0 + row) * (size_t)DV_;
                #pragma unroll
                for (int nt = 0; nt < 8; ++nt)
                    Og[ob + nt * 16 + n16] =
                        (o[qs][nt][r] + oxch[row * 128 + nt * 16 + n16]) * inv;
            }
    }
}

// ---------------- fallback (R4 kernel, used only if workspace too small) ----------------
#define BQ_FB 64
#define LDQ  136
#define LDK  136
#define LDVT 72
#define LDP  72

__global__ __launch_bounds__(256, 2)
void fattn_fb(const float* __restrict__ Qg, const float* __restrict__ Kg,
              const float* __restrict__ Vg, const int* __restrict__ Mg,
              float* __restrict__ Og)
{
    __shared__ u16 Qs[BQ_FB * LDQ];
    __shared__ u16 Ks[BK * LDK];
    __shared__ u16 Vt[DV_ * LDVT];
    __shared__ u16 Ps[4 * 16 * LDP];

    const int tid  = threadIdx.x;
    const int wave = tid >> 6;
    const int lane = tid & 63;
    const int n16  = lane & 15;
    const int quad = lane >> 4;

    const int raw = blockIdx.x;
    const int xcd = raw & 7;
    const int j   = raw >> 3;
    const int b   = xcd * 2 + (j & 1);
    const int q0  = (j >> 1) << 6;

    const int srow = tid >> 4;
    const int scol = (tid & 15) * 8;
    const int vrot = (tid & 7) * 8;

    {
        const float* src = Qg + ((size_t)b * SQ_ + q0) * D_;
        #pragma unroll
        for (int c = 0; c < 4; ++c) {
            int row = c * 16 + srow;
            float4 v0 = *(const float4*)(&src[row * D_ + scol]);
            float4 v1 = *(const float4*)(&src[row * D_ + scol + 4]);
            uint4 pk = { pk2(v0.x, v0.y), pk2(v0.z, v0.w),
                         pk2(v1.x, v1.y), pk2(v1.z, v1.w) };
            *(uint4*)(&Qs[row * LDQ + scol]) = pk;
        }
    }
    __syncthreads();

    s16x8 aQ[4];
    {
        const int qr = wave * 16 + n16;
        #pragma unroll
        for (int kb = 0; kb < 4; ++kb)
            aQ[kb] = *(const s16x8*)(&Qs[qr * LDQ + kb * 32 + quad * 8]);
    }

    f32x4 o[8];
    #pragma unroll
    for (int i = 0; i < 8; ++i) o[i] = (f32x4){0.f, 0.f, 0.f, 0.f};
    float l_part[4] = {0.f, 0.f, 0.f, 0.f};

    const size_t mask_qbase = ((size_t)b * SQ_ + q0 + wave * 16 + quad * 4) * (size_t)SK_;
    const float* baseK = Kg + ((size_t)b * SK_) * D_;
    const float* baseV = Vg + ((size_t)b * SK_) * DV_;

    float4 kf[8], vf[8];
    #pragma unroll
    for (int c = 0; c < 4; ++c) {
        int row = c * 16 + srow;
        kf[2*c]   = *(const float4*)(&baseK[row * D_ + scol]);
        kf[2*c+1] = *(const float4*)(&baseK[row * D_ + scol + 4]);
        vf[2*c]   = *(const float4*)(&baseV[row * DV_ + scol]);
        vf[2*c+1] = *(const float4*)(&baseV[row * DV_ + scol + 4]);
    }
    int mkc[4][4], mkn[4][4];
    #pragma unroll
    for (int t = 0; t < 4; ++t)
        #pragma unroll
        for (int r = 0; r < 4; ++r)
            mkc[t][r] = Mg[mask_qbase + (size_t)r * SK_ + (t * 16 + n16)];

    for (int it = 0; it < NT; ++it) {
        __syncthreads();
        #pragma unroll
        for (int c = 0; c < 4; ++c) {
            int row = c * 16 + srow;
            uint4 pk = { pk2(kf[2*c].x, kf[2*c].y),     pk2(kf[2*c].z, kf[2*c].w),
                         pk2(kf[2*c+1].x, kf[2*c+1].y), pk2(kf[2*c+1].z, kf[2*c+1].w) };
            *(uint4*)(&Ks[row * LDK + scol]) = pk;
        }
        #pragma unroll
        for (int c = 0; c < 4; ++c) {
            int k    = c * 16 + srow;
            int rcol = (k + vrot) & 63;
            int dv0  = scol;
            u32 r0 = pk2(vf[2*c].x,   vf[2*c].y);
            u32 r1 = pk2(vf[2*c].z,   vf[2*c].w);
            u32 r2 = pk2(vf[2*c+1].x, vf[2*c+1].y);
            u32 r3 = pk2(vf[2*c+1].z, vf[2*c+1].w);
            Vt[(dv0 + 0) * LDVT + rcol] = (u16)r0;
            Vt[(dv0 + 1) * LDVT + rcol] = (u16)(r0 >> 16);
            Vt[(dv0 + 2) * LDVT + rcol] = (u16)r1;
            Vt[(dv0 + 3) * LDVT + rcol] = (u16)(r1 >> 16);
            Vt[(dv0 + 4) * LDVT + rcol] = (u16)r2;
            Vt[(dv0 + 5) * LDVT + rcol] = (u16)(r2 >> 16);
            Vt[(dv0 + 6) * LDVT + rcol] = (u16)r3;
            Vt[(dv0 + 7) * LDVT + rcol] = (u16)(r3 >> 16);
        }
        if (it + 1 < NT) {
            const int k0n = (it + 1) * BK;
            #pragma unroll
            for (int c = 0; c < 4; ++c) {
                int row = k0n + c * 16 + srow;
                kf[2*c]   = *(const float4*)(&baseK[row * D_ + scol]);
                kf[2*c+1] = *(const float4*)(&baseK[row * D_ + scol + 4]);
                vf[2*c]   = *(const float4*)(&baseV[row * DV_ + scol]);
                vf[2*c+1] = *(const float4*)(&baseV[row * DV_ + scol + 4]);
            }
            #pragma unroll
            for (int t = 0; t < 4; ++t)
                #pragma unroll
                for (int r = 0; r < 4; ++r)
                    mkn[t][r] = Mg[mask_qbase + (size_t)r * SK_ + (k0n + t * 16 + n16)];
        }
        __syncthreads();

        f32x4 s[4];
        #pragma unroll
        for (int t = 0; t < 4; ++t) s[t] = (f32x4){0.f, 0.f, 0.f, 0.f};
        #pragma unroll
        for (int kb = 0; kb < 4; ++kb) {
            #pragma unroll
            for (int t = 0; t < 4; ++t) {
                s16x8 bK = *(const s16x8*)(&Ks[(t * 16 + n16) * LDK + kb * 32 + quad * 8]);
                s[t] = __builtin_amdgcn_mfma_f32_16x16x32_bf16(aQ[kb], bK, s[t], 0, 0, 0);
            }
        }
        #pragma unroll
        for (int t = 0; t < 4; ++t)
            #pragma unroll
            for (int r = 0; r < 4; ++r) {
                float p = __expf(fmaf(s[t][r], 0.2f, -12.0f));
                l_part[r] += p;
                float pv = mkc[t][r] ? p : 0.f;
                Ps[(wave * 16 + quad * 4 + r) * LDP + t * 16 + n16] = f2bf(pv);
            }
        #pragma unroll
        for (int kk = 0; kk < 2; ++kk) {
            s16x8 aP = *(const s16x8*)(&Ps[(wave * 16 + n16) * LDP + kk * 32 + quad * 8]);
            #pragma unroll
            for (int nt = 0; nt < 8; ++nt) {
                int dv   = nt * 16 + n16;
                int rcol = (kk * 32 + quad * 8 + 8 * ((dv >> 3) & 7)) & 63;
                s16x8 bV = *(const s16x8*)(&Vt[dv * LDVT + rcol]);
                o[nt] = __builtin_amdgcn_mfma_f32_16x16x32_bf16(aP, bV, o[nt], 0, 0, 0);
            }
        }
        #pragma unroll
        for (int t = 0; t < 4; ++t)
            #pragma unroll
            for (int r = 0; r < 4; ++r) mkc[t][r] = mkn[t][r];
    }

    const float keep_scale = 1.0f / 0.9f;
    #pragma unroll
    for (int r = 0; r < 4; ++r) {
        float l = l_part[r];
        #pragma unroll
        for (int off = 1; off < 16; off <<= 1)
            l += __shfl_xor(l, off);
        float inv_l = keep_scale / l;
        size_t obase = ((size_t)b * SQ_ + q0 + wave * 16 + quad * 4 + r) * DV_;
        #pragma unroll
        for (int nt = 0; nt < 8; ++nt)
            Og[obase + nt * 16 + n16] = o[nt][r] * inv_l;
    }
}

extern "C" void kernel_launch(void* const* d_in, const int* in_sizes, int n_in,
                              void* d_out, int out_size, void* d_ws, size_t ws_size,
                              hipStream_t stream) {
    const float* Qg = (const float*)d_in[0];
    const float* Kg = (const float*)d_in[1];
    const float* Vg = (const float*)d_in[2];
    const int*   Mg = (const int*)d_in[3];
    float* Og = (float*)d_out;
    if (d_ws != nullptr && ws_size >= (size_t)16 * 1024 * 1024) {
        u16* Kz = (u16*)d_ws;                   // 8 MB swizzled bf16 K
        u16* Vz = Kz + 4194304;                 // 8 MB transposed+swizzled bf16 V
        prep_k<<<dim3(2048), 256, 0, stream>>>(Kg, Kz);
        prep_v<<<dim3(2048), 256, 0, stream>>>(Vg, Vz);
        fattn_main<<<dim3(512), 256, 0, stream>>>(Qg, Kz, Vz, Mg, Og);
    } else {
        fattn_fb<<<dim3(512), 256, 0, stream>>>(Qg, Kg, Vg, Mg, Og);
    }
}